// Round 4
// baseline (8623.730 us; speedup 1.0000x reference)
//
#include <hip/hip_runtime.h>

#define DECAY   0.6f
#define THRESH  0.6f
#define TSTEPS  28
#define NI      28
#define NH      512
#define BTOT    4096
#define BR      16
#define NTHREADS 1024

__device__ __forceinline__ float sigmoidf_(float z) {
    return 1.0f / (1.0f + expf(-z));
}

// Persistent fused HNN kernel: each block owns BR=16 batch rows for all T steps.
// 1024 threads: thread (rg,cg) rg=tid>>8 (wave-uniform), cg=tid&255.
// Tile: 4 rows (r0..r0+3) x 2 cols (j0,j0+1). 16 waves/CU (4/SIMD) to hide
// L2 weight-load latency (round-3 profile: 2 waves/SIMD -> VALUBusy 44%).
// Row-value LDS reads are wave-uniform (broadcast); weight loads are
// lane-contiguous float2 (512 B/wave coalesced).
__global__ __launch_bounds__(NTHREADS, 4)
void hnn_fused(const float* __restrict__ x,
               const float* __restrict__ fc1s,   // snn_fc1 [28][512]
               const float* __restrict__ fc2s,   // snn_fc2 [1024][512]
               const float* __restrict__ fc1r,   // rnn_fc1 [28][512]
               const float* __restrict__ fc2r,   // rnn_fc2 [1024][512]
               const float* __restrict__ fv1,    // rnn_fv1 [512][512]
               const float* __restrict__ fv2,    // rnn_fv2 [512][512]
               const float* __restrict__ fcw,    // fc_w [10][1024]
               const float* __restrict__ fcb,    // fc_b [10]
               float* __restrict__ out)          // logits[4096*10] | h1y | h2y
{
    const int tid = threadIdx.x;
    const int rg  = tid >> 8;          // 0..3 (wave-uniform)
    const int cg  = tid & 255;         // 0..255
    const int j0  = cg << 1;           // column base (2 cols/thread)
    const int r0  = rg << 2;           // row base (4 rows/thread)
    const int rb  = blockIdx.x * BR;

    extern __shared__ char smem[];
    float* sh_x   = (float*)smem;                 // [BR][784]
    float* sh_h1y = sh_x + BR * 784;              // [BR][512]
    float* sh_h2y = sh_h1y + BR * NH;             // [BR][512]
    unsigned char* sh_spk = (unsigned char*)(sh_h2y + BR * NH); // [BR][512]

    for (int i = tid; i < BR * NH; i += NTHREADS) { sh_h1y[i] = 0.0f; sh_h2y[i] = 0.0f; }
    {   // stage this block's 16 x-rows (50 KB) into LDS once
        const float4* src = (const float4*)(x + (size_t)rb * 784);
        float4* dst = (float4*)sh_x;
        for (int i = tid; i < BR * 784 / 4; i += NTHREADS) dst[i] = src[i];
    }
    __syncthreads();

    float h1mem[4][2], h2mem[4][2], h2sum[4][2];
    #pragma unroll
    for (int m = 0; m < 4; ++m)
        #pragma unroll
        for (int c = 0; c < 2; ++c) { h1mem[m][c] = 0.f; h2mem[m][c] = 0.f; h2sum[m][c] = 0.f; }

    for (int t = 0; t < TSTEPS; ++t) {
        float accS[4][2], accR[4][2];
        #pragma unroll
        for (int m = 0; m < 4; ++m)
            #pragma unroll
            for (int c = 0; c < 2; ++c) { accS[m][c] = 0.f; accR[m][c] = 0.f; }

        // ---- layer 1: x_t @ fc1s and x_t @ fc1r (K=28); x_t[r][i] = x[r][i*28+t]
        #pragma unroll 4
        for (int k = 0; k < NI; ++k) {
            const float2 ws = *(const float2*)(fc1s + k * NH + j0);
            const float2 wr = *(const float2*)(fc1r + k * NH + j0);
            #pragma unroll
            for (int m = 0; m < 4; ++m) {
                const float xv = sh_x[(r0 + m) * 784 + k * 28 + t];
                accS[m][0] += xv * ws.x; accS[m][1] += xv * ws.y;
                accR[m][0] += xv * wr.x; accR[m][1] += xv * wr.y;
            }
        }
        // ---- layer 1: h1y_prev @ fv1 (K=512) into accR
        #pragma unroll 2
        for (int k4 = 0; k4 < NH; k4 += 4) {
            float4 hv[4];
            #pragma unroll
            for (int m = 0; m < 4; ++m)
                hv[m] = *(const float4*)(sh_h1y + (r0 + m) * NH + k4);
            #pragma unroll
            for (int kk = 0; kk < 4; ++kk) {
                const float2 w = *(const float2*)(fv1 + (k4 + kk) * NH + j0);
                #pragma unroll
                for (int m = 0; m < 4; ++m) {
                    const float h = ((const float*)&hv[m])[kk];
                    accR[m][0] += h * w.x; accR[m][1] += h * w.y;
                }
            }
        }
        // membrane update, spike bytes, new h1y (regs)
        float h1y_new[4][2];
        #pragma unroll
        for (int m = 0; m < 4; ++m) {
            uchar2 sb;
            unsigned char sp[2];
            #pragma unroll
            for (int c = 0; c < 2; ++c) {
                float mem = h1mem[m][c];
                // prev spike recomputed from prev mem: spk = (mem > THRESH)
                mem = (mem > THRESH ? 0.0f : mem * DECAY) + accS[m][c];
                h1mem[m][c] = mem;
                sp[c] = (mem > THRESH) ? (unsigned char)1 : (unsigned char)0;
                h1y_new[m][c] = sigmoidf_(accR[m][c]);
            }
            sb.x = sp[0]; sb.y = sp[1];
            *(uchar2*)(sh_spk + (r0 + m) * NH + j0) = sb;  // read only after next 2 barriers
        }
        __syncthreads();          // all fv1 reads of old h1y done
        #pragma unroll
        for (int m = 0; m < 4; ++m) {
            float2 v; v.x = h1y_new[m][0]; v.y = h1y_new[m][1];
            *(float2*)(sh_h1y + (r0 + m) * NH + j0) = v;
        }
        __syncthreads();          // h1y + spikes visible

        // ---- layer 2 ----
        #pragma unroll
        for (int m = 0; m < 4; ++m)
            #pragma unroll
            for (int c = 0; c < 2; ++c) { accS[m][c] = 0.f; accR[m][c] = 0.f; }

        // o1 spike half (K=512): wave-uniform conditional adds (skips loads too)
        #pragma unroll 1
        for (int k4 = 0; k4 < NH; k4 += 4) {
            unsigned u[4];
            #pragma unroll
            for (int m = 0; m < 4; ++m)
                u[m] = *(const unsigned*)(sh_spk + (r0 + m) * NH + k4);
            const unsigned any = u[0] | u[1] | u[2] | u[3];
            if (any == 0u) continue;
            #pragma unroll
            for (int kk = 0; kk < 4; ++kk) {
                if ((any >> (8 * kk)) & 0xffu) {
                    const float2 ws = *(const float2*)(fc2s + (k4 + kk) * NH + j0);
                    const float2 wr = *(const float2*)(fc2r + (k4 + kk) * NH + j0);
                    #pragma unroll
                    for (int m = 0; m < 4; ++m) {
                        if ((u[m] >> (8 * kk)) & 0xffu) {
                            accS[m][0] += ws.x; accS[m][1] += ws.y;
                            accR[m][0] += wr.x; accR[m][1] += wr.y;
                        }
                    }
                }
            }
        }
        // o1 h1y half (K=512): weight rows 512..1023
        #pragma unroll 2
        for (int k4 = 0; k4 < NH; k4 += 4) {
            float4 hv[4];
            #pragma unroll
            for (int m = 0; m < 4; ++m)
                hv[m] = *(const float4*)(sh_h1y + (r0 + m) * NH + k4);
            #pragma unroll
            for (int kk = 0; kk < 4; ++kk) {
                const float2 ws = *(const float2*)(fc2s + (NH + k4 + kk) * NH + j0);
                const float2 wr = *(const float2*)(fc2r + (NH + k4 + kk) * NH + j0);
                #pragma unroll
                for (int m = 0; m < 4; ++m) {
                    const float h = ((const float*)&hv[m])[kk];
                    accS[m][0] += h * ws.x; accS[m][1] += h * ws.y;
                    accR[m][0] += h * wr.x; accR[m][1] += h * wr.y;
                }
            }
        }
        // h2y_prev @ fv2 (K=512) into accR
        #pragma unroll 2
        for (int k4 = 0; k4 < NH; k4 += 4) {
            float4 hv[4];
            #pragma unroll
            for (int m = 0; m < 4; ++m)
                hv[m] = *(const float4*)(sh_h2y + (r0 + m) * NH + k4);
            #pragma unroll
            for (int kk = 0; kk < 4; ++kk) {
                const float2 w = *(const float2*)(fv2 + (k4 + kk) * NH + j0);
                #pragma unroll
                for (int m = 0; m < 4; ++m) {
                    const float h = ((const float*)&hv[m])[kk];
                    accR[m][0] += h * w.x; accR[m][1] += h * w.y;
                }
            }
        }
        float h2y_new[4][2];
        #pragma unroll
        for (int m = 0; m < 4; ++m) {
            #pragma unroll
            for (int c = 0; c < 2; ++c) {
                float mem = h2mem[m][c];
                mem = (mem > THRESH ? 0.0f : mem * DECAY) + accS[m][c];
                h2mem[m][c] = mem;
                const float sp = (mem > THRESH) ? 1.0f : 0.0f;
                h2sum[m][c] += sp;
                h2y_new[m][c] = sigmoidf_(accR[m][c]);
            }
        }
        __syncthreads();          // all fv2 reads of old h2y done
        #pragma unroll
        for (int m = 0; m < 4; ++m) {
            float2 v; v.x = h2y_new[m][0]; v.y = h2y_new[m][1];
            *(float2*)(sh_h2y + (r0 + m) * NH + j0) = v;
        }
        __syncthreads();
    }

    // ---- epilogue: h1y, h2y copies + logits ----
    const size_t L_OFF  = (size_t)BTOT * 10;
    const size_t H2_OFF = L_OFF + (size_t)BTOT * NH;
    #pragma unroll
    for (int m = 0; m < 4; ++m) {
        const int r = r0 + m;
        const int row = rb + r;
        *(float2*)(out + L_OFF  + (size_t)row * NH + j0) = *(const float2*)(sh_h1y + r * NH + j0);
        *(float2*)(out + H2_OFF + (size_t)row * NH + j0) = *(const float2*)(sh_h2y + r * NH + j0);
    }
    float* sh_sum = sh_x;   // reuse x slab for h2_sum/T (x no longer read)
    #pragma unroll
    for (int m = 0; m < 4; ++m)
        #pragma unroll
        for (int c = 0; c < 2; ++c)
            sh_sum[(r0 + m) * NH + j0 + c] = h2sum[m][c] * (1.0f / (float)TSTEPS);
    __syncthreads();
    if (tid < BR * 10) {
        const int r = tid / 10;
        const int c = tid % 10;
        float acc = fcb[c];
        for (int k = 0; k < NH; ++k) acc += sh_sum[r * NH + k] * fcw[c * 1024 + k];
        for (int k = 0; k < NH; ++k) acc += sh_h2y[r * NH + k] * fcw[c * 1024 + NH + k];
        out[(size_t)(rb + r) * 10 + c] = acc;
    }
}

extern "C" void kernel_launch(void* const* d_in, const int* in_sizes, int n_in,
                              void* d_out, int out_size, void* d_ws, size_t ws_size,
                              hipStream_t stream) {
    (void)in_sizes; (void)n_in; (void)out_size; (void)d_ws; (void)ws_size;
    const float* x    = (const float*)d_in[0];
    // d_in[1], d_in[2] (hidden1/hidden2) are zero-valued and unused by the reference math
    const float* fc1s = (const float*)d_in[3];
    const float* fc2s = (const float*)d_in[4];
    const float* fc1r = (const float*)d_in[5];
    const float* fc2r = (const float*)d_in[6];
    const float* fv1  = (const float*)d_in[7];
    const float* fv2  = (const float*)d_in[8];
    const float* fcw  = (const float*)d_in[9];
    const float* fcb  = (const float*)d_in[10];
    float* out = (float*)d_out;

    const size_t smem = (size_t)(BR * 784 + 2 * BR * NH) * sizeof(float) + (size_t)BR * NH; // 123904 B
    hipFuncSetAttribute(reinterpret_cast<const void*>(hnn_fused),
                        hipFuncAttributeMaxDynamicSharedMemorySize, (int)smem);
    hipLaunchKernelGGL(hnn_fused, dim3(BTOT / BR), dim3(NTHREADS), smem, stream,
                       x, fc1s, fc2s, fc1r, fc2r, fv1, fv2, fcw, fcb, out);
}

// Round 5
// 6603.074 us; speedup vs baseline: 1.3060x; 1.3060x over previous
//
#include <hip/hip_runtime.h>

#define DECAY   0.6f
#define THRESH  0.6f
#define TSTEPS  28
#define NH      512
#define BTOT    4096
#define BR      16
#define NTHREADS 512

// ---- packed-weight layout in d_ws (fp32, fragment-major) ----
// For each matrix W[K][512]: P[kb][j][kk] = W[4*kb+kk][512j... flat:
//   P_flat[(kb*512 + j)*4 + kk] = W[(4*kb+kk)*512 + j]
// One float4 load per thread covers 4 consecutive K-rows of its column.
// Offsets in float4 units:
#define F4_FV1   0         // 512x512  -> 65536 f4
#define F4_FV2   65536     // 512x512
#define F4_FC2S  131072    // 1024x512 -> 131072 f4
#define F4_FC2R  262144
#define F4_TOTAL 393216    // 6 MB

__global__ __launch_bounds__(256) void pack_w(const float* __restrict__ fv1,
                                              const float* __restrict__ fv2,
                                              const float* __restrict__ fc2s,
                                              const float* __restrict__ fc2r,
                                              float4* __restrict__ wsp) {
    int i = blockIdx.x * blockDim.x + threadIdx.x;
    if (i >= F4_TOTAL) return;
    const float* src;
    int pos = i;
    if (pos < F4_FV2)            { src = fv1; }
    else if (pos < F4_FC2S)      { src = fv2;  pos -= F4_FV2; }
    else if (pos < F4_FC2R)      { src = fc2s; pos -= F4_FC2S; }
    else                         { src = fc2r; pos -= F4_FC2R; }
    const int kb = pos >> 9;          // pos / 512
    const int j  = pos & 511;
    float4 v;
    v.x = src[(kb * 4 + 0) * NH + j];
    v.y = src[(kb * 4 + 1) * NH + j];
    v.z = src[(kb * 4 + 2) * NH + j];
    v.w = src[(kb * 4 + 3) * NH + j];
    wsp[i] = v;
}

__device__ __forceinline__ float sigmoidf_(float z) {
    return 1.0f / (1.0f + expf(-z));
}

// Column-split persistent kernel. Block = 16 batch rows, 512 threads:
//   rg = tid>>8 (0..1, wave-uniform): rows rg*8 .. rg*8+7
//   jp = tid&255: columns 2*jp, 2*jp+1
// Each thread: 8 rows x 2 cols. Weight redundancy per block = 2x (two row
// groups) -> L1 line traffic 2*6.2MB/step/CU (round-3 tiling was 4x = the
// measured 44%-VALUBusy L1-bound wall). h/spk broadcast from LDS is
// wave-uniform float4 (no conflicts); weight loads lane-contiguous dwordx4.
__global__ __launch_bounds__(NTHREADS, 2)
void hnn_fused(const float* __restrict__ x,
               const float* __restrict__ fc1s,   // snn_fc1 [28][512]
               const float* __restrict__ fc1r,   // rnn_fc1 [28][512]
               const float4* __restrict__ wsp,   // packed fv1|fv2|fc2s|fc2r
               const float* __restrict__ fcw,    // fc_w [10][1024]
               const float* __restrict__ fcb,    // fc_b [10]
               float* __restrict__ out)          // logits | h1y | h2y
{
    const int tid = threadIdx.x;
    const int rg  = tid >> 8;          // wave-uniform
    const int jp  = tid & 255;
    const int j2  = jp << 1;           // first of the 2 owned columns
    const int r0  = rg << 3;           // row base (8 rows)
    const int rb  = blockIdx.x * BR;

    const float4* __restrict__ fv1p  = wsp + F4_FV1;
    const float4* __restrict__ fv2p  = wsp + F4_FV2;
    const float4* __restrict__ fc2sp = wsp + F4_FC2S;
    const float4* __restrict__ fc2rp = wsp + F4_FC2R;

    extern __shared__ char smem[];
    float* sh_h1y = (float*)smem;                 // [16][512] 32KB
    float* sh_spk = sh_h1y + BR * NH;             // [16][512] 32KB
    float* sh_h2y = sh_spk + BR * NH;             // [16][512] 32KB
    float* sh_xt  = sh_h2y + BR * NH;             // [32][16]  2KB (k-major)

    for (int i = tid; i < BR * NH; i += NTHREADS) { sh_h1y[i] = 0.0f; sh_h2y[i] = 0.0f; }
    sh_xt[tid] = 0.0f;                            // covers all 32*16, incl. k=28..31 pad
    __syncthreads();

    const float4* __restrict__ h1p  = (const float4*)sh_h1y;  // [16][128] f4 view
    const float4* __restrict__ spkp = (const float4*)sh_spk;
    const float4* __restrict__ h2p  = (const float4*)sh_h2y;

    float h1mem[8][2], h2mem[8][2], h2sum[8][2];
    #pragma unroll
    for (int r = 0; r < 8; ++r)
        #pragma unroll
        for (int c = 0; c < 2; ++c) { h1mem[r][c] = 0.f; h2mem[r][c] = 0.f; h2sum[r][c] = 0.f; }

    for (int t = 0; t < TSTEPS; ++t) {
        // stage x_t: xt[k][r] = x[rb+r][k*28+t]
        if (tid < 448) {
            const int k = tid >> 4, r = tid & 15;
            sh_xt[k * 16 + r] = x[(size_t)(rb + r) * 784 + k * 28 + t];
        }
        __syncthreads();   // xt visible; also orders prev-step h2y write before fv2 reads

        float accS[8][2], accR[8][2];
        #pragma unroll
        for (int r = 0; r < 8; ++r)
            #pragma unroll
            for (int c = 0; c < 2; ++c) { accS[r][c] = 0.f; accR[r][c] = 0.f; }

        // ---- layer 1: x_t @ fc1s / x_t @ fc1r (K=28)
        #pragma unroll 4
        for (int k = 0; k < 28; ++k) {
            const float2 ws1 = *(const float2*)(fc1s + k * NH + j2);
            const float2 wr1 = *(const float2*)(fc1r + k * NH + j2);
            const float4 xa = *(const float4*)(sh_xt + k * 16 + r0);
            const float4 xb = *(const float4*)(sh_xt + k * 16 + r0 + 4);
            const float xv[8] = {xa.x, xa.y, xa.z, xa.w, xb.x, xb.y, xb.z, xb.w};
            #pragma unroll
            for (int r = 0; r < 8; ++r) {
                accS[r][0] += xv[r] * ws1.x; accS[r][1] += xv[r] * ws1.y;
                accR[r][0] += xv[r] * wr1.x; accR[r][1] += xv[r] * wr1.y;
            }
        }
        // ---- layer 1 recurrent: h1y_prev @ fv1 (K=512)
        #pragma unroll 2
        for (int kb = 0; kb < 128; ++kb) {
            const float4 wa = fv1p[kb * NH + j2];
            const float4 wb = fv1p[kb * NH + j2 + 1];
            #pragma unroll
            for (int r = 0; r < 8; ++r) {
                const float4 h = h1p[(r0 + r) * 128 + kb];
                accR[r][0] += h.x * wa.x + h.y * wa.y + h.z * wa.z + h.w * wa.w;
                accR[r][1] += h.x * wb.x + h.y * wb.y + h.z * wb.z + h.w * wb.w;
            }
        }
        // h1 membrane update; spike + sigmoid (reuse acc arrays as outputs)
        #pragma unroll
        for (int r = 0; r < 8; ++r) {
            #pragma unroll
            for (int c = 0; c < 2; ++c) {
                float mem = h1mem[r][c];
                mem = (mem > THRESH ? 0.0f : mem * DECAY) + accS[r][c];
                h1mem[r][c] = mem;
                accS[r][c] = (mem > THRESH) ? 1.0f : 0.0f;       // spike
                accR[r][c] = sigmoidf_(accR[r][c]);              // h1y_new
            }
        }
        __syncthreads();   // all reads of old h1y done
        #pragma unroll
        for (int r = 0; r < 8; ++r) {
            float2 s; s.x = accS[r][0]; s.y = accS[r][1];
            float2 y; y.x = accR[r][0]; y.y = accR[r][1];
            *(float2*)(sh_spk + (r0 + r) * NH + j2) = s;
            *(float2*)(sh_h1y + (r0 + r) * NH + j2) = y;
        }
        __syncthreads();   // new h1y + spk visible

        // ---- layer 2: o1=[spk|h1y] @ fc2s / fc2r (K=1024), + h2y_prev @ fv2
        #pragma unroll
        for (int r = 0; r < 8; ++r)
            #pragma unroll
            for (int c = 0; c < 2; ++c) { accS[r][c] = 0.f; accR[r][c] = 0.f; }

        #pragma unroll 2
        for (int kb = 0; kb < 128; ++kb) {       // spike half (fc2 rows 0..511)
            const float4 sa = fc2sp[kb * NH + j2];
            const float4 sb = fc2sp[kb * NH + j2 + 1];
            const float4 ra = fc2rp[kb * NH + j2];
            const float4 rb4 = fc2rp[kb * NH + j2 + 1];
            #pragma unroll
            for (int r = 0; r < 8; ++r) {
                const float4 h = spkp[(r0 + r) * 128 + kb];
                accS[r][0] += h.x * sa.x + h.y * sa.y + h.z * sa.z + h.w * sa.w;
                accS[r][1] += h.x * sb.x + h.y * sb.y + h.z * sb.z + h.w * sb.w;
                accR[r][0] += h.x * ra.x + h.y * ra.y + h.z * ra.z + h.w * ra.w;
                accR[r][1] += h.x * rb4.x + h.y * rb4.y + h.z * rb4.z + h.w * rb4.w;
            }
        }
        #pragma unroll 2
        for (int kb = 0; kb < 128; ++kb) {       // h1y half (fc2 rows 512..1023)
            const float4 sa = fc2sp[(128 + kb) * NH + j2];
            const float4 sb = fc2sp[(128 + kb) * NH + j2 + 1];
            const float4 ra = fc2rp[(128 + kb) * NH + j2];
            const float4 rb4 = fc2rp[(128 + kb) * NH + j2 + 1];
            #pragma unroll
            for (int r = 0; r < 8; ++r) {
                const float4 h = h1p[(r0 + r) * 128 + kb];
                accS[r][0] += h.x * sa.x + h.y * sa.y + h.z * sa.z + h.w * sa.w;
                accS[r][1] += h.x * sb.x + h.y * sb.y + h.z * sb.z + h.w * sb.w;
                accR[r][0] += h.x * ra.x + h.y * ra.y + h.z * ra.z + h.w * ra.w;
                accR[r][1] += h.x * rb4.x + h.y * rb4.y + h.z * rb4.z + h.w * rb4.w;
            }
        }
        #pragma unroll 2
        for (int kb = 0; kb < 128; ++kb) {       // h2y_prev @ fv2
            const float4 wa = fv2p[kb * NH + j2];
            const float4 wb = fv2p[kb * NH + j2 + 1];
            #pragma unroll
            for (int r = 0; r < 8; ++r) {
                const float4 h = h2p[(r0 + r) * 128 + kb];
                accR[r][0] += h.x * wa.x + h.y * wa.y + h.z * wa.z + h.w * wa.w;
                accR[r][1] += h.x * wb.x + h.y * wb.y + h.z * wb.z + h.w * wb.w;
            }
        }
        // h2 membrane update
        #pragma unroll
        for (int r = 0; r < 8; ++r) {
            #pragma unroll
            for (int c = 0; c < 2; ++c) {
                float mem = h2mem[r][c];
                mem = (mem > THRESH ? 0.0f : mem * DECAY) + accS[r][c];
                h2mem[r][c] = mem;
                h2sum[r][c] += (mem > THRESH) ? 1.0f : 0.0f;
                accR[r][c] = sigmoidf_(accR[r][c]);              // h2y_new
            }
        }
        __syncthreads();   // all reads of old h2y done
        #pragma unroll
        for (int r = 0; r < 8; ++r) {
            float2 y; y.x = accR[r][0]; y.y = accR[r][1];
            *(float2*)(sh_h2y + (r0 + r) * NH + j2) = y;
        }
        __syncthreads();
    }

    // ---- epilogue ----
    const size_t L_OFF  = (size_t)BTOT * 10;
    const size_t H2_OFF = L_OFF + (size_t)BTOT * NH;
    #pragma unroll
    for (int r = 0; r < 8; ++r) {
        const int row = rb + r0 + r;
        *(float2*)(out + L_OFF  + (size_t)row * NH + j2) = *(const float2*)(sh_h1y + (r0 + r) * NH + j2);
        *(float2*)(out + H2_OFF + (size_t)row * NH + j2) = *(const float2*)(sh_h2y + (r0 + r) * NH + j2);
    }
    // h2_sum/T into sh_spk (spk no longer needed)
    #pragma unroll
    for (int r = 0; r < 8; ++r) {
        float2 s; s.x = h2sum[r][0] * (1.0f / (float)TSTEPS);
        s.y = h2sum[r][1] * (1.0f / (float)TSTEPS);
        *(float2*)(sh_spk + (r0 + r) * NH + j2) = s;
    }
    __syncthreads();
    if (tid < BR * 10) {
        const int r = tid / 10;
        const int c = tid % 10;
        float acc = fcb[c];
        for (int k = 0; k < NH; ++k) acc += sh_spk[r * NH + k] * fcw[c * 1024 + k];
        for (int k = 0; k < NH; ++k) acc += sh_h2y[r * NH + k] * fcw[c * 1024 + NH + k];
        out[(size_t)(rb + r) * 10 + c] = acc;
    }
}

extern "C" void kernel_launch(void* const* d_in, const int* in_sizes, int n_in,
                              void* d_out, int out_size, void* d_ws, size_t ws_size,
                              hipStream_t stream) {
    (void)in_sizes; (void)n_in; (void)out_size; (void)ws_size;
    const float* x    = (const float*)d_in[0];
    // d_in[1], d_in[2] (hidden1/hidden2) are zero-valued and unused by the reference math
    const float* fc1s = (const float*)d_in[3];
    const float* fc2s = (const float*)d_in[4];
    const float* fc1r = (const float*)d_in[5];
    const float* fc2r = (const float*)d_in[6];
    const float* fv1  = (const float*)d_in[7];
    const float* fv2  = (const float*)d_in[8];
    const float* fcw  = (const float*)d_in[9];
    const float* fcb  = (const float*)d_in[10];
    float* out = (float*)d_out;
    float4* wsp = (float4*)d_ws;    // 6 MB packed weights

    hipLaunchKernelGGL(pack_w, dim3((F4_TOTAL + 255) / 256), dim3(256), 0, stream,
                       fv1, fv2, fc2s, fc2r, wsp);

    const size_t smem = (size_t)(3 * BR * NH + 32 * 16) * sizeof(float); // 100352 B
    hipFuncSetAttribute(reinterpret_cast<const void*>(hnn_fused),
                        hipFuncAttributeMaxDynamicSharedMemorySize, (int)smem);
    hipLaunchKernelGGL(hnn_fused, dim3(BTOT / BR), dim3(NTHREADS), smem, stream,
                       x, fc1s, fc1r, wsp, fcw, fcb, out);
}

// Round 6
// 3323.383 us; speedup vs baseline: 2.5949x; 1.9869x over previous
//
#include <hip/hip_runtime.h>

#define DECAY   0.6f
#define THRESH  0.6f
#define TSTEPS  28
#define NH      512
#define BTOT    4096
#define BR      16
#define NTHREADS 512
#define SP      520          // padded ushort stride for [16][512] LDS arrays (2-way banks max)
#define XS      40           // padded ushort stride for [16][32] x arrays

typedef short s16x8 __attribute__((ext_vector_type(8)));
typedef float f32x4 __attribute__((ext_vector_type(4)));
typedef unsigned int u32x4 __attribute__((ext_vector_type(4)));

__device__ __host__ __forceinline__ unsigned short f2bf(float x) {
    union { float f; unsigned u; } v; v.f = x;
    unsigned u = v.u + 0x7FFFu + ((v.u >> 16) & 1u);   // RNE
    return (unsigned short)(u >> 16);
}
__device__ __forceinline__ float bf2f(unsigned short b) {
    union { unsigned u; float f; } v; v.u = ((unsigned)b) << 16;
    return v.f;
}
__device__ __forceinline__ f32x4 fzero() { f32x4 z = {0.f, 0.f, 0.f, 0.f}; return z; }

// ---------- packed weight fragments in d_ws (ushort offsets) ----------
// For W[K][512]: frag(s,n,L,e) = bf16( W[32s + 8*(L>>4) + e][16n + (L&15)] )
// flat: pk[O + ((s*32 + n)*64 + L)*8 + e]  -> one coalesced 16B load per lane.
#define LEN_S     16384      // ushorts per K-step (32 n-tiles * 64 lanes * 8)
#define O_FC1S_HI 0
#define O_FC1S_LO (O_FC1S_HI + 1*LEN_S)
#define O_FC1R_HI (O_FC1S_LO + 1*LEN_S)
#define O_FC1R_LO (O_FC1R_HI + 1*LEN_S)
#define O_FV1_HI  (O_FC1R_LO + 1*LEN_S)
#define O_FV1_LO  (O_FV1_HI + 16*LEN_S)
#define O_FV2_HI  (O_FV1_LO + 16*LEN_S)
#define O_FV2_LO  (O_FV2_HI + 16*LEN_S)
#define O_FC2S_HI (O_FV2_LO + 16*LEN_S)
#define O_FC2S_LO (O_FC2S_HI + 32*LEN_S)
#define O_FC2R_HI (O_FC2S_LO + 32*LEN_S)
#define O_FC2R_LO (O_FC2R_HI + 32*LEN_S)
#define PK_TOTAL  (O_FC2R_LO + 32*LEN_S)   // 3,211,264 ushort = 6.42 MB

__global__ __launch_bounds__(256)
void pack_w(const float* __restrict__ fc1s, const float* __restrict__ fc1r,
            const float* __restrict__ fv1,  const float* __restrict__ fv2,
            const float* __restrict__ fc2s, const float* __restrict__ fc2r,
            unsigned short* __restrict__ pk)
{
    const int f = blockIdx.x * 256 + threadIdx.x;   // fragment id (s,n,L)
    const float* src; int Ksrc; unsigned ohi, olo; int local;
    if      (f < 2048)   { src = fc1s; Ksrc = 28;   ohi = O_FC1S_HI; olo = O_FC1S_LO; local = f; }
    else if (f < 4096)   { src = fc1r; Ksrc = 28;   ohi = O_FC1R_HI; olo = O_FC1R_LO; local = f - 2048; }
    else if (f < 36864)  { src = fv1;  Ksrc = 512;  ohi = O_FV1_HI;  olo = O_FV1_LO;  local = f - 4096; }
    else if (f < 69632)  { src = fv2;  Ksrc = 512;  ohi = O_FV2_HI;  olo = O_FV2_LO;  local = f - 36864; }
    else if (f < 135168) { src = fc2s; Ksrc = 1024; ohi = O_FC2S_HI; olo = O_FC2S_LO; local = f - 69632; }
    else if (f < 200704) { src = fc2r; Ksrc = 1024; ohi = O_FC2R_HI; olo = O_FC2R_LO; local = f - 135168; }
    else return;
    const int L  = local & 63;
    const int n  = (local >> 6) & 31;
    const int s  = local >> 11;
    const int c  = n * 16 + (L & 15);
    const int k0 = s * 32 + (L >> 4) * 8;
    unsigned short hb[8], lb[8];
    #pragma unroll
    for (int e = 0; e < 8; ++e) {
        const int k = k0 + e;
        const float w = (k < Ksrc) ? src[k * NH + c] : 0.0f;
        const unsigned short h = f2bf(w);
        hb[e] = h;
        lb[e] = f2bf(w - bf2f(h));
    }
    *(u32x4*)(pk + ohi + (unsigned)local * 8) = *(const u32x4*)hb;
    *(u32x4*)(pk + olo + (unsigned)local * 8) = *(const u32x4*)lb;
}

#define MFMA(a, b, c) __builtin_amdgcn_mfma_f32_16x16x32_bf16((a), (b), (c), 0, 0, 0)
// A-frag (row = lane&15, k = 32s + 8*(lane>>4) + e) from padded LDS ushort array
#define LDSA(arr, s) __builtin_bit_cast(s16x8, *(const u32x4*)((arr) + lrow * SP + (s) * 32 + lgrp * 8))
#define LDSAX(arr)   __builtin_bit_cast(s16x8, *(const u32x4*)((arr) + lrow * XS + lgrp * 8))
// B-frag from packed global
#define GLB(base, s, n) __builtin_bit_cast(s16x8, *(const u32x4*)(pk + (base) + (unsigned)((((s) * 32 + (n)) * 64 + lane) * 8)))

// Persistent MFMA kernel: block = 16 batch rows x all 512 cols, 8 waves,
// wave w owns N-tiles 4w..4w+3. All GEMMs are split-bf16 (hi+lo) MFMA:
// W.h = Whi.hhi + Whi.hlo + Wlo.hhi (spikes exact in bf16 -> 2 products).
// Membranes/sigmoid/spike logic fp32 in D-layout regs (lane: row=(lane>>4)*4+r,
// col=16n+(lane&15), m89-verified). 4 barriers/step.
__global__ __launch_bounds__(NTHREADS, 2)
void hnn_mfma(const float* __restrict__ x,
              const unsigned short* __restrict__ pk,
              const float* __restrict__ fcw,
              const float* __restrict__ fcb,
              float* __restrict__ out)
{
    const int tid  = threadIdx.x;
    const int lane = tid & 63;
    const int wid  = tid >> 6;          // 0..7
    const int lrow = lane & 15;
    const int lgrp = lane >> 4;         // 0..3
    const int rb   = blockIdx.x * BR;

    extern __shared__ char smem[];
    float* sh_x = (float*)smem;                          // [16][784] fp32; reused as sums[16][512] in epilogue
    unsigned short* sh   = (unsigned short*)(sh_x + BR * 784);
    unsigned short* h1hi = sh;                           // [16][SP]
    unsigned short* h1lo = h1hi + BR * SP;
    unsigned short* hspk = h1lo + BR * SP;
    unsigned short* h2hi = hspk + BR * SP;
    unsigned short* h2lo = h2hi + BR * SP;
    unsigned short* xhi  = h2lo + BR * SP;               // [16][XS]
    unsigned short* xlo  = xhi + BR * XS;

    for (int i = tid; i < 5 * BR * SP + 2 * BR * XS; i += NTHREADS) sh[i] = 0;
    {
        const float4* src = (const float4*)(x + (size_t)rb * 784);
        float4* dst = (float4*)sh_x;
        for (int i = tid; i < BR * 784 / 4; i += NTHREADS) dst[i] = src[i];
    }

    f32x4 h1mem[4], h2mem[4], h2sum[4];
    #pragma unroll
    for (int n4 = 0; n4 < 4; ++n4) { h1mem[n4] = fzero(); h2mem[n4] = fzero(); h2sum[n4] = fzero(); }

    for (int t = 0; t < TSTEPS; ++t) {
        // stage x_t split: xt[r][k] = x[rb+r][k*28+t], k padded to 32 with zeros (init)
        if (tid < 448) {
            const int k = tid >> 4, r = tid & 15;
            const float v = sh_x[r * 784 + k * 28 + t];
            const unsigned short h = f2bf(v);
            xhi[r * XS + k] = h;
            xlo[r * XS + k] = f2bf(v - bf2f(h));
        }
        __syncthreads();   // (A) x split + prev-step h2 writes visible

        f32x4 accS[4], accR[4];
        #pragma unroll
        for (int n4 = 0; n4 < 4; ++n4) { accS[n4] = fzero(); accR[n4] = fzero(); }

        // ---- layer 1 input: x_t @ fc1s / fc1r (K=32 incl. zero pad)
        {
            const s16x8 axh = LDSAX(xhi), axl = LDSAX(xlo);
            #pragma unroll
            for (int n4 = 0; n4 < 4; ++n4) {
                const int n = wid * 4 + n4;
                const s16x8 bsh = GLB(O_FC1S_HI, 0, n), bsl = GLB(O_FC1S_LO, 0, n);
                const s16x8 brh = GLB(O_FC1R_HI, 0, n), brl = GLB(O_FC1R_LO, 0, n);
                accS[n4] = MFMA(axh, bsh, accS[n4]);
                accS[n4] = MFMA(axl, bsh, accS[n4]);
                accS[n4] = MFMA(axh, bsl, accS[n4]);
                accR[n4] = MFMA(axh, brh, accR[n4]);
                accR[n4] = MFMA(axl, brh, accR[n4]);
                accR[n4] = MFMA(axh, brl, accR[n4]);
            }
        }
        // ---- layer 1 recurrent: h1y_prev @ fv1
        #pragma unroll 2
        for (int s = 0; s < 16; ++s) {
            const s16x8 ah = LDSA(h1hi, s), al = LDSA(h1lo, s);
            #pragma unroll
            for (int n4 = 0; n4 < 4; ++n4) {
                const int n = wid * 4 + n4;
                const s16x8 bh = GLB(O_FV1_HI, s, n), bl = GLB(O_FV1_LO, s, n);
                accR[n4] = MFMA(ah, bh, accR[n4]);
                accR[n4] = MFMA(al, bh, accR[n4]);
                accR[n4] = MFMA(ah, bl, accR[n4]);
            }
        }
        // membrane 1 update; spike + sigmoid splits (regs)
        unsigned short spv[4][4], yh[4][4], yl[4][4];
        #pragma unroll
        for (int n4 = 0; n4 < 4; ++n4) {
            #pragma unroll
            for (int r = 0; r < 4; ++r) {
                float mem = h1mem[n4][r];
                mem = (mem > THRESH ? 0.0f : mem * DECAY) + accS[n4][r];
                h1mem[n4][r] = mem;
                spv[n4][r] = (mem > THRESH) ? (unsigned short)0x3F80 : (unsigned short)0;  // bf16 1.0/0.0
                const float y = 1.0f / (1.0f + expf(-accR[n4][r]));
                const unsigned short h = f2bf(y);
                yh[n4][r] = h;
                yl[n4][r] = f2bf(y - bf2f(h));
            }
        }
        __syncthreads();   // (B) all fv1 reads of old h1 arrays done
        #pragma unroll
        for (int n4 = 0; n4 < 4; ++n4) {
            const int col = (wid * 4 + n4) * 16 + lrow;
            #pragma unroll
            for (int r = 0; r < 4; ++r) {
                const int row = lgrp * 4 + r;
                hspk[row * SP + col] = spv[n4][r];
                h1hi[row * SP + col] = yh[n4][r];
                h1lo[row * SP + col] = yl[n4][r];
            }
        }
        __syncthreads();   // (C) new h1/spk visible

        // ---- layer 2 ----
        #pragma unroll
        for (int n4 = 0; n4 < 4; ++n4) { accS[n4] = fzero(); accR[n4] = fzero(); }

        #pragma unroll 2
        for (int s = 0; s < 16; ++s) {          // o1 spike half (fc2 rows 0..511); spikes exact bf16
            const s16x8 asp = LDSA(hspk, s);
            #pragma unroll
            for (int n4 = 0; n4 < 4; ++n4) {
                const int n = wid * 4 + n4;
                const s16x8 bsh = GLB(O_FC2S_HI, s, n), bsl = GLB(O_FC2S_LO, s, n);
                const s16x8 brh = GLB(O_FC2R_HI, s, n), brl = GLB(O_FC2R_LO, s, n);
                accS[n4] = MFMA(asp, bsh, accS[n4]);
                accS[n4] = MFMA(asp, bsl, accS[n4]);
                accR[n4] = MFMA(asp, brh, accR[n4]);
                accR[n4] = MFMA(asp, brl, accR[n4]);
            }
        }
        #pragma unroll 2
        for (int s = 0; s < 16; ++s) {          // o1 h1y half (fc2 rows 512..1023)
            const s16x8 ah = LDSA(h1hi, s), al = LDSA(h1lo, s);
            #pragma unroll
            for (int n4 = 0; n4 < 4; ++n4) {
                const int n = wid * 4 + n4;
                const s16x8 bsh = GLB(O_FC2S_HI, s + 16, n), bsl = GLB(O_FC2S_LO, s + 16, n);
                const s16x8 brh = GLB(O_FC2R_HI, s + 16, n), brl = GLB(O_FC2R_LO, s + 16, n);
                accS[n4] = MFMA(ah, bsh, accS[n4]);
                accS[n4] = MFMA(al, bsh, accS[n4]);
                accS[n4] = MFMA(ah, bsl, accS[n4]);
                accR[n4] = MFMA(ah, brh, accR[n4]);
                accR[n4] = MFMA(al, brh, accR[n4]);
                accR[n4] = MFMA(ah, brl, accR[n4]);
            }
        }
        #pragma unroll 2
        for (int s = 0; s < 16; ++s) {          // h2y_prev @ fv2
            const s16x8 ah = LDSA(h2hi, s), al = LDSA(h2lo, s);
            #pragma unroll
            for (int n4 = 0; n4 < 4; ++n4) {
                const int n = wid * 4 + n4;
                const s16x8 bh = GLB(O_FV2_HI, s, n), bl = GLB(O_FV2_LO, s, n);
                accR[n4] = MFMA(ah, bh, accR[n4]);
                accR[n4] = MFMA(al, bh, accR[n4]);
                accR[n4] = MFMA(ah, bl, accR[n4]);
            }
        }
        // membrane 2 update
        #pragma unroll
        for (int n4 = 0; n4 < 4; ++n4) {
            #pragma unroll
            for (int r = 0; r < 4; ++r) {
                float mem = h2mem[n4][r];
                mem = (mem > THRESH ? 0.0f : mem * DECAY) + accS[n4][r];
                h2mem[n4][r] = mem;
                h2sum[n4][r] += (mem > THRESH) ? 1.0f : 0.0f;
                const float y = 1.0f / (1.0f + expf(-accR[n4][r]));
                const unsigned short h = f2bf(y);
                yh[n4][r] = h;
                yl[n4][r] = f2bf(y - bf2f(h));
            }
        }
        __syncthreads();   // (D) all fv2 reads of old h2 arrays done
        #pragma unroll
        for (int n4 = 0; n4 < 4; ++n4) {
            const int col = (wid * 4 + n4) * 16 + lrow;
            #pragma unroll
            for (int r = 0; r < 4; ++r) {
                const int row = lgrp * 4 + r;
                h2hi[row * SP + col] = yh[n4][r];
                h2lo[row * SP + col] = yl[n4][r];
            }
        }
        // visibility for next step's fv2 reads is barrier (A)
    }
    __syncthreads();

    // ---- epilogue ----
    float* sums = sh_x;   // reuse x slab (fp32 [16][512])
    #pragma unroll
    for (int n4 = 0; n4 < 4; ++n4) {
        const int col = (wid * 4 + n4) * 16 + lrow;
        #pragma unroll
        for (int r = 0; r < 4; ++r)
            sums[(lgrp * 4 + r) * NH + col] = h2sum[n4][r] * (1.0f / (float)TSTEPS);
    }
    const size_t L_OFF  = (size_t)BTOT * 10;
    const size_t H2_OFF = L_OFF + (size_t)BTOT * NH;
    for (int i = tid; i < BR * NH; i += NTHREADS) {
        const int r = i >> 9, c = i & 511;
        out[L_OFF  + (size_t)(rb + r) * NH + c] = bf2f(h1hi[r * SP + c]) + bf2f(h1lo[r * SP + c]);
        out[H2_OFF + (size_t)(rb + r) * NH + c] = bf2f(h2hi[r * SP + c]) + bf2f(h2lo[r * SP + c]);
    }
    __syncthreads();
    if (tid < BR * 10) {
        const int r = tid / 10, c = tid % 10;
        float acc = fcb[c];
        for (int k = 0; k < NH; ++k) acc += sums[r * NH + k] * fcw[c * 1024 + k];
        for (int k = 0; k < NH; ++k)
            acc += (bf2f(h2hi[r * SP + k]) + bf2f(h2lo[r * SP + k])) * fcw[c * 1024 + NH + k];
        out[(size_t)(rb + r) * 10 + c] = acc;
    }
}

extern "C" void kernel_launch(void* const* d_in, const int* in_sizes, int n_in,
                              void* d_out, int out_size, void* d_ws, size_t ws_size,
                              hipStream_t stream) {
    (void)in_sizes; (void)n_in; (void)out_size; (void)ws_size;
    const float* x    = (const float*)d_in[0];
    // d_in[1], d_in[2] (hidden1/hidden2) zero-valued, unused by reference math
    const float* fc1s = (const float*)d_in[3];
    const float* fc2s = (const float*)d_in[4];
    const float* fc1r = (const float*)d_in[5];
    const float* fc2r = (const float*)d_in[6];
    const float* fv1  = (const float*)d_in[7];
    const float* fv2  = (const float*)d_in[8];
    const float* fcw  = (const float*)d_in[9];
    const float* fcb  = (const float*)d_in[10];
    float* out = (float*)d_out;
    unsigned short* pk = (unsigned short*)d_ws;     // 6.42 MB packed split-bf16 weights

    hipLaunchKernelGGL(pack_w, dim3((200704 + 255) / 256), dim3(256), 0, stream,
                       fc1s, fc1r, fv1, fv2, fc2s, fc2r, pk);

    const size_t smem = (size_t)(BR * 784) * sizeof(float)
                      + (size_t)(5 * BR * SP + 2 * BR * XS) * sizeof(unsigned short); // 135,936 B
    hipFuncSetAttribute(reinterpret_cast<const void*>(hnn_mfma),
                        hipFuncAttributeMaxDynamicSharedMemorySize, (int)smem);
    hipLaunchKernelGGL(hnn_mfma, dim3(BTOT / BR), dim3(NTHREADS), smem, stream,
                       x, pk, fcw, fcb, out);
}

// Round 7
// 2359.504 us; speedup vs baseline: 3.6549x; 1.4085x over previous
//
#include <hip/hip_runtime.h>

#define DECAY   0.6f
#define THRESH  0.6f
#define TSTEPS  28
#define NH      512
#define BTOT    4096
#define BR      16
#define NTHREADS 1024
#define SP      520          // padded ushort stride for [16][512] LDS arrays (2-way banks max)
#define XS      40           // padded ushort stride for [16][32] x arrays

typedef short s16x8 __attribute__((ext_vector_type(8)));
typedef float f32x4 __attribute__((ext_vector_type(4)));
typedef unsigned int u32x4 __attribute__((ext_vector_type(4)));

__device__ __host__ __forceinline__ unsigned short f2bf(float x) {
    union { float f; unsigned u; } v; v.f = x;
    unsigned u = v.u + 0x7FFFu + ((v.u >> 16) & 1u);   // RNE
    return (unsigned short)(u >> 16);
}
__device__ __forceinline__ float bf2f(unsigned short b) {
    union { unsigned u; float f; } v; v.u = ((unsigned)b) << 16;
    return v.f;
}
__device__ __forceinline__ f32x4 fzero() { f32x4 z = {0.f, 0.f, 0.f, 0.f}; return z; }

// ---------- packed weight fragments in d_ws (ushort offsets) ----------
// For W[K][512]: frag(s,n,L,e) = bf16( W[32s + 8*(L>>4) + e][16n + (L&15)] )
// flat: pk[O + ((s*32 + n)*64 + L)*8 + e]  -> one coalesced 16B load per lane.
#define LEN_S     16384      // ushorts per K-step (32 n-tiles * 64 lanes * 8)
#define O_FC1S_HI 0
#define O_FC1S_LO (O_FC1S_HI + 1*LEN_S)
#define O_FC1R_HI (O_FC1S_LO + 1*LEN_S)
#define O_FC1R_LO (O_FC1R_HI + 1*LEN_S)
#define O_FV1_HI  (O_FC1R_LO + 1*LEN_S)
#define O_FV1_LO  (O_FV1_HI + 16*LEN_S)
#define O_FV2_HI  (O_FV1_LO + 16*LEN_S)
#define O_FV2_LO  (O_FV2_HI + 16*LEN_S)
#define O_FC2S_HI (O_FV2_LO + 16*LEN_S)
#define O_FC2S_LO (O_FC2S_HI + 32*LEN_S)
#define O_FC2R_HI (O_FC2S_LO + 32*LEN_S)
#define O_FC2R_LO (O_FC2R_HI + 32*LEN_S)
#define PK_TOTAL  (O_FC2R_LO + 32*LEN_S)   // 3,211,264 ushort = 6.42 MB

__global__ __launch_bounds__(256)
void pack_w(const float* __restrict__ fc1s, const float* __restrict__ fc1r,
            const float* __restrict__ fv1,  const float* __restrict__ fv2,
            const float* __restrict__ fc2s, const float* __restrict__ fc2r,
            unsigned short* __restrict__ pk)
{
    const int f = blockIdx.x * 256 + threadIdx.x;   // fragment id (s,n,L)
    const float* src; int Ksrc; unsigned ohi, olo; int local;
    if      (f < 2048)   { src = fc1s; Ksrc = 28;   ohi = O_FC1S_HI; olo = O_FC1S_LO; local = f; }
    else if (f < 4096)   { src = fc1r; Ksrc = 28;   ohi = O_FC1R_HI; olo = O_FC1R_LO; local = f - 2048; }
    else if (f < 36864)  { src = fv1;  Ksrc = 512;  ohi = O_FV1_HI;  olo = O_FV1_LO;  local = f - 4096; }
    else if (f < 69632)  { src = fv2;  Ksrc = 512;  ohi = O_FV2_HI;  olo = O_FV2_LO;  local = f - 36864; }
    else if (f < 135168) { src = fc2s; Ksrc = 1024; ohi = O_FC2S_HI; olo = O_FC2S_LO; local = f - 69632; }
    else if (f < 200704) { src = fc2r; Ksrc = 1024; ohi = O_FC2R_HI; olo = O_FC2R_LO; local = f - 135168; }
    else return;
    const int L  = local & 63;
    const int n  = (local >> 6) & 31;
    const int s  = local >> 11;
    const int c  = n * 16 + (L & 15);
    const int k0 = s * 32 + (L >> 4) * 8;
    unsigned short hb[8], lb[8];
    #pragma unroll
    for (int e = 0; e < 8; ++e) {
        const int k = k0 + e;
        const float w = (k < Ksrc) ? src[k * NH + c] : 0.0f;
        const unsigned short h = f2bf(w);
        hb[e] = h;
        lb[e] = f2bf(w - bf2f(h));
    }
    *(u32x4*)(pk + ohi + (unsigned)local * 8) = *(const u32x4*)hb;
    *(u32x4*)(pk + olo + (unsigned)local * 8) = *(const u32x4*)lb;
}

#define MFMA(a, b, c) __builtin_amdgcn_mfma_f32_16x16x32_bf16((a), (b), (c), 0, 0, 0)
// A-frag (row = lane&15, k = 32s + 8*(lane>>4) + e) from padded LDS ushort array
#define LDSA(arr, s) __builtin_bit_cast(s16x8, *(const u32x4*)((arr) + lrow * SP + (s) * 32 + lgrp * 8))
#define LDSAX(arr)   __builtin_bit_cast(s16x8, *(const u32x4*)((arr) + lrow * XS + lgrp * 8))
// B-frag from packed global
#define GLB(base, s, n) __builtin_bit_cast(s16x8, *(const u32x4*)(pk + (base) + (unsigned)((((s) * 32 + (n)) * 64 + lane) * 8)))

// Persistent MFMA kernel: block = 16 batch rows x all 512 cols, 16 waves,
// wave w owns N-tiles 2w..2w+1 (round-7: was 8 waves x 4 tiles; 4 waves/SIMD
// to hide L2 weight-stream latency — round-6 achieved only 22 B/cyc/CU vs
// 60 B/cyc ceiling at 2 waves/SIMD). Per-column accumulation order is
// bit-identical to round 6. Split-bf16 (hi+lo): W.h = Whi.hhi + Whi.hlo +
// Wlo.hhi (spikes exact in bf16 -> 2 products). 4 barriers/step.
__global__ __launch_bounds__(NTHREADS, 4)
void hnn_mfma(const float* __restrict__ x,
              const unsigned short* __restrict__ pk,
              const float* __restrict__ fcw,
              const float* __restrict__ fcb,
              float* __restrict__ out)
{
    const int tid  = threadIdx.x;
    const int lane = tid & 63;
    const int wid  = tid >> 6;          // 0..15
    const int lrow = lane & 15;
    const int lgrp = lane >> 4;         // 0..3
    const int rb   = blockIdx.x * BR;

    extern __shared__ char smem[];
    float* sh_x = (float*)smem;                          // [16][784] fp32; reused as sums[16][512] in epilogue
    unsigned short* sh   = (unsigned short*)(sh_x + BR * 784);
    unsigned short* h1hi = sh;                           // [16][SP]
    unsigned short* h1lo = h1hi + BR * SP;
    unsigned short* hspk = h1lo + BR * SP;
    unsigned short* h2hi = hspk + BR * SP;
    unsigned short* h2lo = h2hi + BR * SP;
    unsigned short* xhi  = h2lo + BR * SP;               // [16][XS]
    unsigned short* xlo  = xhi + BR * XS;

    for (int i = tid; i < 5 * BR * SP + 2 * BR * XS; i += NTHREADS) sh[i] = 0;
    {
        const float4* src = (const float4*)(x + (size_t)rb * 784);
        float4* dst = (float4*)sh_x;
        for (int i = tid; i < BR * 784 / 4; i += NTHREADS) dst[i] = src[i];
    }

    f32x4 h1mem[2], h2mem[2], h2sum[2];
    #pragma unroll
    for (int n4 = 0; n4 < 2; ++n4) { h1mem[n4] = fzero(); h2mem[n4] = fzero(); h2sum[n4] = fzero(); }

    for (int t = 0; t < TSTEPS; ++t) {
        // stage x_t split: xt[r][k] = x[rb+r][k*28+t], k padded to 32 with zeros (init)
        if (tid < 448) {
            const int k = tid >> 4, r = tid & 15;
            const float v = sh_x[r * 784 + k * 28 + t];
            const unsigned short h = f2bf(v);
            xhi[r * XS + k] = h;
            xlo[r * XS + k] = f2bf(v - bf2f(h));
        }
        __syncthreads();   // (A) x split + prev-step h2 writes visible

        f32x4 accS[2], accR[2];
        #pragma unroll
        for (int n4 = 0; n4 < 2; ++n4) { accS[n4] = fzero(); accR[n4] = fzero(); }

        // ---- layer 1 input: x_t @ fc1s / fc1r (K=32 incl. zero pad)
        {
            const s16x8 axh = LDSAX(xhi), axl = LDSAX(xlo);
            #pragma unroll
            for (int n4 = 0; n4 < 2; ++n4) {
                const int n = wid * 2 + n4;
                const s16x8 bsh = GLB(O_FC1S_HI, 0, n), bsl = GLB(O_FC1S_LO, 0, n);
                const s16x8 brh = GLB(O_FC1R_HI, 0, n), brl = GLB(O_FC1R_LO, 0, n);
                accS[n4] = MFMA(axh, bsh, accS[n4]);
                accS[n4] = MFMA(axl, bsh, accS[n4]);
                accS[n4] = MFMA(axh, bsl, accS[n4]);
                accR[n4] = MFMA(axh, brh, accR[n4]);
                accR[n4] = MFMA(axl, brh, accR[n4]);
                accR[n4] = MFMA(axh, brl, accR[n4]);
            }
        }
        // ---- layer 1 recurrent: h1y_prev @ fv1
        #pragma unroll 2
        for (int s = 0; s < 16; ++s) {
            const s16x8 ah = LDSA(h1hi, s), al = LDSA(h1lo, s);
            #pragma unroll
            for (int n4 = 0; n4 < 2; ++n4) {
                const int n = wid * 2 + n4;
                const s16x8 bh = GLB(O_FV1_HI, s, n), bl = GLB(O_FV1_LO, s, n);
                accR[n4] = MFMA(ah, bh, accR[n4]);
                accR[n4] = MFMA(al, bh, accR[n4]);
                accR[n4] = MFMA(ah, bl, accR[n4]);
            }
        }
        // membrane 1 update; spike + sigmoid splits (regs)
        unsigned short spv[2][4], yh[2][4], yl[2][4];
        #pragma unroll
        for (int n4 = 0; n4 < 2; ++n4) {
            #pragma unroll
            for (int r = 0; r < 4; ++r) {
                float mem = h1mem[n4][r];
                mem = (mem > THRESH ? 0.0f : mem * DECAY) + accS[n4][r];
                h1mem[n4][r] = mem;
                spv[n4][r] = (mem > THRESH) ? (unsigned short)0x3F80 : (unsigned short)0;  // bf16 1.0/0.0
                const float y = 1.0f / (1.0f + expf(-accR[n4][r]));
                const unsigned short h = f2bf(y);
                yh[n4][r] = h;
                yl[n4][r] = f2bf(y - bf2f(h));
            }
        }
        __syncthreads();   // (B) all fv1 reads of old h1 arrays done
        #pragma unroll
        for (int n4 = 0; n4 < 2; ++n4) {
            const int col = (wid * 2 + n4) * 16 + lrow;
            #pragma unroll
            for (int r = 0; r < 4; ++r) {
                const int row = lgrp * 4 + r;
                hspk[row * SP + col] = spv[n4][r];
                h1hi[row * SP + col] = yh[n4][r];
                h1lo[row * SP + col] = yl[n4][r];
            }
        }
        __syncthreads();   // (C) new h1/spk visible

        // ---- layer 2 ----
        #pragma unroll
        for (int n4 = 0; n4 < 2; ++n4) { accS[n4] = fzero(); accR[n4] = fzero(); }

        #pragma unroll 2
        for (int s = 0; s < 16; ++s) {          // o1 spike half (fc2 rows 0..511); spikes exact bf16
            const s16x8 asp = LDSA(hspk, s);
            #pragma unroll
            for (int n4 = 0; n4 < 2; ++n4) {
                const int n = wid * 2 + n4;
                const s16x8 bsh = GLB(O_FC2S_HI, s, n), bsl = GLB(O_FC2S_LO, s, n);
                const s16x8 brh = GLB(O_FC2R_HI, s, n), brl = GLB(O_FC2R_LO, s, n);
                accS[n4] = MFMA(asp, bsh, accS[n4]);
                accS[n4] = MFMA(asp, bsl, accS[n4]);
                accR[n4] = MFMA(asp, brh, accR[n4]);
                accR[n4] = MFMA(asp, brl, accR[n4]);
            }
        }
        #pragma unroll 2
        for (int s = 0; s < 16; ++s) {          // o1 h1y half (fc2 rows 512..1023)
            const s16x8 ah = LDSA(h1hi, s), al = LDSA(h1lo, s);
            #pragma unroll
            for (int n4 = 0; n4 < 2; ++n4) {
                const int n = wid * 2 + n4;
                const s16x8 bsh = GLB(O_FC2S_HI, s + 16, n), bsl = GLB(O_FC2S_LO, s + 16, n);
                const s16x8 brh = GLB(O_FC2R_HI, s + 16, n), brl = GLB(O_FC2R_LO, s + 16, n);
                accS[n4] = MFMA(ah, bsh, accS[n4]);
                accS[n4] = MFMA(al, bsh, accS[n4]);
                accS[n4] = MFMA(ah, bsl, accS[n4]);
                accR[n4] = MFMA(ah, brh, accR[n4]);
                accR[n4] = MFMA(al, brh, accR[n4]);
                accR[n4] = MFMA(ah, brl, accR[n4]);
            }
        }
        #pragma unroll 2
        for (int s = 0; s < 16; ++s) {          // h2y_prev @ fv2
            const s16x8 ah = LDSA(h2hi, s), al = LDSA(h2lo, s);
            #pragma unroll
            for (int n4 = 0; n4 < 2; ++n4) {
                const int n = wid * 2 + n4;
                const s16x8 bh = GLB(O_FV2_HI, s, n), bl = GLB(O_FV2_LO, s, n);
                accR[n4] = MFMA(ah, bh, accR[n4]);
                accR[n4] = MFMA(al, bh, accR[n4]);
                accR[n4] = MFMA(ah, bl, accR[n4]);
            }
        }
        // membrane 2 update
        #pragma unroll
        for (int n4 = 0; n4 < 2; ++n4) {
            #pragma unroll
            for (int r = 0; r < 4; ++r) {
                float mem = h2mem[n4][r];
                mem = (mem > THRESH ? 0.0f : mem * DECAY) + accS[n4][r];
                h2mem[n4][r] = mem;
                h2sum[n4][r] += (mem > THRESH) ? 1.0f : 0.0f;
                const float y = 1.0f / (1.0f + expf(-accR[n4][r]));
                const unsigned short h = f2bf(y);
                yh[n4][r] = h;
                yl[n4][r] = f2bf(y - bf2f(h));
            }
        }
        __syncthreads();   // (D) all fv2 reads of old h2 arrays done
        #pragma unroll
        for (int n4 = 0; n4 < 2; ++n4) {
            const int col = (wid * 2 + n4) * 16 + lrow;
            #pragma unroll
            for (int r = 0; r < 4; ++r) {
                const int row = lgrp * 4 + r;
                h2hi[row * SP + col] = yh[n4][r];
                h2lo[row * SP + col] = yl[n4][r];
            }
        }
        // visibility for next step's fv2 reads is barrier (A)
    }
    __syncthreads();

    // ---- epilogue ----
    float* sums = sh_x;   // reuse x slab (fp32 [16][512])
    #pragma unroll
    for (int n4 = 0; n4 < 2; ++n4) {
        const int col = (wid * 2 + n4) * 16 + lrow;
        #pragma unroll
        for (int r = 0; r < 4; ++r)
            sums[(lgrp * 4 + r) * NH + col] = h2sum[n4][r] * (1.0f / (float)TSTEPS);
    }
    const size_t L_OFF  = (size_t)BTOT * 10;
    const size_t H2_OFF = L_OFF + (size_t)BTOT * NH;
    for (int i = tid; i < BR * NH; i += NTHREADS) {
        const int r = i >> 9, c = i & 511;
        out[L_OFF  + (size_t)(rb + r) * NH + c] = bf2f(h1hi[r * SP + c]) + bf2f(h1lo[r * SP + c]);
        out[H2_OFF + (size_t)(rb + r) * NH + c] = bf2f(h2hi[r * SP + c]) + bf2f(h2lo[r * SP + c]);
    }
    __syncthreads();
    if (tid < BR * 10) {
        const int r = tid / 10, c = tid % 10;
        float acc = fcb[c];
        for (int k = 0; k < NH; ++k) acc += sums[r * NH + k] * fcw[c * 1024 + k];
        for (int k = 0; k < NH; ++k)
            acc += (bf2f(h2hi[r * SP + k]) + bf2f(h2lo[r * SP + k])) * fcw[c * 1024 + NH + k];
        out[(size_t)(rb + r) * 10 + c] = acc;
    }
}

extern "C" void kernel_launch(void* const* d_in, const int* in_sizes, int n_in,
                              void* d_out, int out_size, void* d_ws, size_t ws_size,
                              hipStream_t stream) {
    (void)in_sizes; (void)n_in; (void)out_size; (void)ws_size;
    const float* x    = (const float*)d_in[0];
    // d_in[1], d_in[2] (hidden1/hidden2) zero-valued, unused by reference math
    const float* fc1s = (const float*)d_in[3];
    const float* fc2s = (const float*)d_in[4];
    const float* fc1r = (const float*)d_in[5];
    const float* fc2r = (const float*)d_in[6];
    const float* fv1  = (const float*)d_in[7];
    const float* fv2  = (const float*)d_in[8];
    const float* fcw  = (const float*)d_in[9];
    const float* fcb  = (const float*)d_in[10];
    float* out = (float*)d_out;
    unsigned short* pk = (unsigned short*)d_ws;     // 6.42 MB packed split-bf16 weights

    hipLaunchKernelGGL(pack_w, dim3((200704 + 255) / 256), dim3(256), 0, stream,
                       fc1s, fc1r, fv1, fv2, fc2s, fc2r, pk);

    const size_t smem = (size_t)(BR * 784) * sizeof(float)
                      + (size_t)(5 * BR * SP + 2 * BR * XS) * sizeof(unsigned short); // 135,936 B
    hipFuncSetAttribute(reinterpret_cast<const void*>(hnn_mfma),
                        hipFuncAttributeMaxDynamicSharedMemorySize, (int)smem);
    hipLaunchKernelGGL(hnn_mfma, dim3(BTOT / BR), dim3(NTHREADS), smem, stream,
                       x, pk, fcw, fcb, out);
}

// Round 11
// 1738.928 us; speedup vs baseline: 4.9592x; 1.3569x over previous
//
#include <hip/hip_runtime.h>

#define DECAY   0.6f
#define THRESH  0.6f
#define TSTEPS  28
#define NH      512
#define BTOT    4096
#define BR      16
#define NTHREADS 1024
#define XS      40           // padded ushort stride for [16][32] x arrays

typedef short s16x8 __attribute__((ext_vector_type(8)));
typedef float f32x4 __attribute__((ext_vector_type(4)));
typedef unsigned int u32x4 __attribute__((ext_vector_type(4)));

__device__ __host__ __forceinline__ unsigned short f2bf(float x) {
    union { float f; unsigned u; } v; v.f = x;
    unsigned u = v.u + 0x7FFFu + ((v.u >> 16) & 1u);   // RNE
    return (unsigned short)(u >> 16);
}
__device__ __forceinline__ float bf2f(unsigned short b) {
    union { unsigned u; float f; } v; v.u = ((unsigned)b) << 16;
    return v.f;
}
__device__ __forceinline__ f32x4 fzero() { f32x4 z = {0.f, 0.f, 0.f, 0.f}; return z; }

// ---------- packed weight fragments in d_ws (ushort offsets) ----------
// For W[K][512]: frag(s,n,L,e) = bf16( W[32s + 8*(L>>4) + e][16n + (L&15)] )
// flat: pk[O + ((s*32 + n)*64 + L)*8 + e]  -> one coalesced 16B load per lane.
// hi+lo ONLY for the h1-path (fc1s, fc1r, fv1) so h1 membranes/spikes stay
// bit-identical to rounds 6/7; h2-path (fv2, fc2s, fc2r) is hi-only.
// Total 3.80 MB < 4 MiB per-XCD L2 -> weights L2-resident across steps
// (round-7 FETCH showed 6.42 MB cycling through L2 = 85 us/step refill wall).
#define LEN_S     16384      // ushorts per K-step (32 n-tiles * 64 lanes * 8)
#define O_FC1S_HI (0*LEN_S)
#define O_FC1S_LO (1*LEN_S)
#define O_FC1R_HI (2*LEN_S)
#define O_FC1R_LO (3*LEN_S)
#define O_FV1_HI  (4*LEN_S)    // 16 LEN_S
#define O_FV1_LO  (20*LEN_S)   // 16
#define O_FV2_HI  (36*LEN_S)   // 16
#define O_FC2S_HI (52*LEN_S)   // 32
#define O_FC2R_HI (84*LEN_S)   // 32
#define PK_TOTAL  (116*LEN_S)  // 1,900,544 ushort = 3.80 MB

__global__ __launch_bounds__(256)
void pack_w(const float* __restrict__ fc1s, const float* __restrict__ fc1r,
            const float* __restrict__ fv1,  const float* __restrict__ fv2,
            const float* __restrict__ fc2s, const float* __restrict__ fc2r,
            unsigned short* __restrict__ pk)
{
    const int f = blockIdx.x * 256 + threadIdx.x;   // fragment id (s,n,L)
    const float* src; int Ksrc; unsigned ohi, olo; int local; bool has_lo;
    if      (f < 2048)   { src = fc1s; Ksrc = 28;   ohi = O_FC1S_HI; olo = O_FC1S_LO; local = f;          has_lo = true;  }
    else if (f < 4096)   { src = fc1r; Ksrc = 28;   ohi = O_FC1R_HI; olo = O_FC1R_LO; local = f - 2048;   has_lo = true;  }
    else if (f < 36864)  { src = fv1;  Ksrc = 512;  ohi = O_FV1_HI;  olo = O_FV1_LO;  local = f - 4096;   has_lo = true;  }
    else if (f < 69632)  { src = fv2;  Ksrc = 512;  ohi = O_FV2_HI;  olo = 0;         local = f - 36864;  has_lo = false; }
    else if (f < 135168) { src = fc2s; Ksrc = 1024; ohi = O_FC2S_HI; olo = 0;         local = f - 69632;  has_lo = false; }
    else if (f < 200704) { src = fc2r; Ksrc = 1024; ohi = O_FC2R_HI; olo = 0;         local = f - 135168; has_lo = false; }
    else return;
    const int L  = local & 63;
    const int n  = (local >> 6) & 31;
    const int s  = local >> 11;
    const int c  = n * 16 + (L & 15);
    const int k0 = s * 32 + (L >> 4) * 8;
    unsigned short hb[8], lb[8];
    #pragma unroll
    for (int e = 0; e < 8; ++e) {
        const int k = k0 + e;
        const float w = (k < Ksrc) ? src[k * NH + c] : 0.0f;
        const unsigned short h = f2bf(w);
        hb[e] = h;
        lb[e] = f2bf(w - bf2f(h));
    }
    *(u32x4*)(pk + ohi + (unsigned)local * 8) = *(const u32x4*)hb;
    if (has_lo)
        *(u32x4*)(pk + olo + (unsigned)local * 8) = *(const u32x4*)lb;
}

#define MFMA(a, b, c) __builtin_amdgcn_mfma_f32_16x16x32_bf16((a), (b), (c), 0, 0, 0)
// A-frag (row = lane&15, k = 32s + 8*(lane>>4) + e) from XOR-swizzled LDS:
// ushort idx = row*512 + (col16 ^ ((row&7)<<3)). Row stride 1024 B == 0 mod
// bank-wrap; the XOR spreads the 16 lrow lanes across 8 distinct 16-B slots
// -> 2 lanes/slot = conflict-free (G4; round-7 SP=520 padding measured 5.5e7
// conflict cycles ~ 3.7%).
#define LDSA(arr, s) __builtin_bit_cast(s16x8, *(const u32x4*)((arr) + lrow * 512 + ((((s) * 32) + lgrp * 8) ^ swz)))
#define LDSAX(arr)   __builtin_bit_cast(s16x8, *(const u32x4*)((arr) + lrow * XS + lgrp * 8))
// B-frag from packed global
#define GLB(base, s, n) __builtin_bit_cast(s16x8, *(const u32x4*)(pk + (base) + (unsigned)((((s) * 32 + (n)) * 64 + lane) * 8)))

// Persistent MFMA kernel: block = 16 batch rows x all 512 cols, 16 waves,
// wave w owns N-tiles 2w..2w+1 (4 waves/SIMD). Split-bf16: h1 path exact
// (Whi.hhi + Whi.hlo + Wlo.hhi); h2 path hi-only (Whi.hhi + Whi.hlo) --
// h2 spikes don't recurse (h2_spk only feeds h2_sum), so 2^-9 W-error there
// cannot avalanche. 4 barriers/step.
__global__ __launch_bounds__(NTHREADS, 4)
void hnn_mfma(const float* __restrict__ x,
              const unsigned short* __restrict__ pk,
              const float* __restrict__ fcw,
              const float* __restrict__ fcb,
              float* __restrict__ out)
{
    const int tid  = threadIdx.x;
    const int lane = tid & 63;
    const int wid  = tid >> 6;          // 0..15
    const int lrow = lane & 15;
    const int lgrp = lane >> 4;         // 0..3
    const int swz  = (lrow & 7) << 3;   // read-side XOR (ushort units)
    const int rb   = blockIdx.x * BR;

    extern __shared__ char smem[];
    float* sh_x = (float*)smem;                          // [16][784] fp32; reused as sums[16][512] in epilogue
    unsigned short* sh   = (unsigned short*)(sh_x + BR * 784);
    unsigned short* h1hi = sh;                           // [16][512] swizzled
    unsigned short* h1lo = h1hi + BR * 512;
    unsigned short* hspk = h1lo + BR * 512;
    unsigned short* h2hi = hspk + BR * 512;
    unsigned short* h2lo = h2hi + BR * 512;
    unsigned short* xhi  = h2lo + BR * 512;              // [16][XS], unswizzled
    unsigned short* xlo  = xhi + BR * XS;

    for (int i = tid; i < 5 * BR * 512 + 2 * BR * XS; i += NTHREADS) sh[i] = 0;
    {
        const float4* src = (const float4*)(x + (size_t)rb * 784);
        float4* dst = (float4*)sh_x;
        for (int i = tid; i < BR * 784 / 4; i += NTHREADS) dst[i] = src[i];
    }

    f32x4 h1mem[2], h2mem[2], h2sum[2];
    #pragma unroll
    for (int n4 = 0; n4 < 2; ++n4) { h1mem[n4] = fzero(); h2mem[n4] = fzero(); h2sum[n4] = fzero(); }

    for (int t = 0; t < TSTEPS; ++t) {
        // stage x_t split: xt[r][k] = x[rb+r][k*28+t], k padded to 32 with zeros (init)
        if (tid < 448) {
            const int k = tid >> 4, r = tid & 15;
            const float v = sh_x[r * 784 + k * 28 + t];
            const unsigned short h = f2bf(v);
            xhi[r * XS + k] = h;
            xlo[r * XS + k] = f2bf(v - bf2f(h));
        }
        __syncthreads();   // (A) x split + prev-step h2 writes visible

        f32x4 accS[2], accR[2];
        #pragma unroll
        for (int n4 = 0; n4 < 2; ++n4) { accS[n4] = fzero(); accR[n4] = fzero(); }

        // ---- layer 1 input: x_t @ fc1s / fc1r (K=32 incl. zero pad) — exact split
        {
            const s16x8 axh = LDSAX(xhi), axl = LDSAX(xlo);
            #pragma unroll
            for (int n4 = 0; n4 < 2; ++n4) {
                const int n = wid * 2 + n4;
                const s16x8 bsh = GLB(O_FC1S_HI, 0, n), bsl = GLB(O_FC1S_LO, 0, n);
                const s16x8 brh = GLB(O_FC1R_HI, 0, n), brl = GLB(O_FC1R_LO, 0, n);
                accS[n4] = MFMA(axh, bsh, accS[n4]);
                accS[n4] = MFMA(axl, bsh, accS[n4]);
                accS[n4] = MFMA(axh, bsl, accS[n4]);
                accR[n4] = MFMA(axh, brh, accR[n4]);
                accR[n4] = MFMA(axl, brh, accR[n4]);
                accR[n4] = MFMA(axh, brl, accR[n4]);
            }
        }
        // ---- layer 1 recurrent: h1y_prev @ fv1 — exact split (h1 path bit-identical to r7)
        #pragma unroll 2
        for (int s = 0; s < 16; ++s) {
            const s16x8 ah = LDSA(h1hi, s), al = LDSA(h1lo, s);
            #pragma unroll
            for (int n4 = 0; n4 < 2; ++n4) {
                const int n = wid * 2 + n4;
                const s16x8 bh = GLB(O_FV1_HI, s, n), bl = GLB(O_FV1_LO, s, n);
                accR[n4] = MFMA(ah, bh, accR[n4]);
                accR[n4] = MFMA(al, bh, accR[n4]);
                accR[n4] = MFMA(ah, bl, accR[n4]);
            }
        }
        // membrane 1 update; spike + sigmoid splits (regs)
        unsigned short spv[2][4], yh[2][4], yl[2][4];
        #pragma unroll
        for (int n4 = 0; n4 < 2; ++n4) {
            #pragma unroll
            for (int r = 0; r < 4; ++r) {
                float mem = h1mem[n4][r];
                mem = (mem > THRESH ? 0.0f : mem * DECAY) + accS[n4][r];
                h1mem[n4][r] = mem;
                spv[n4][r] = (mem > THRESH) ? (unsigned short)0x3F80 : (unsigned short)0;  // bf16 1.0/0.0
                const float y = 1.0f / (1.0f + expf(-accR[n4][r]));
                const unsigned short h = f2bf(y);
                yh[n4][r] = h;
                yl[n4][r] = f2bf(y - bf2f(h));
            }
        }
        __syncthreads();   // (B) all fv1 reads of old h1 arrays done
        #pragma unroll
        for (int n4 = 0; n4 < 2; ++n4) {
            const int col = (wid * 2 + n4) * 16 + lrow;
            #pragma unroll
            for (int r = 0; r < 4; ++r) {
                const int row = lgrp * 4 + r;
                const int wc  = row * 512 + (col ^ ((row & 7) << 3));   // write-side XOR
                hspk[wc] = spv[n4][r];
                h1hi[wc] = yh[n4][r];
                h1lo[wc] = yl[n4][r];
            }
        }
        __syncthreads();   // (C) new h1/spk visible

        // ---- layer 2 (hi-only weights) ----
        #pragma unroll
        for (int n4 = 0; n4 < 2; ++n4) { accS[n4] = fzero(); accR[n4] = fzero(); }

        #pragma unroll 2
        for (int s = 0; s < 16; ++s) {          // o1 spike half (fc2 rows 0..511); spikes exact bf16
            const s16x8 asp = LDSA(hspk, s);
            #pragma unroll
            for (int n4 = 0; n4 < 2; ++n4) {
                const int n = wid * 2 + n4;
                const s16x8 bsh = GLB(O_FC2S_HI, s, n);
                const s16x8 brh = GLB(O_FC2R_HI, s, n);
                accS[n4] = MFMA(asp, bsh, accS[n4]);
                accR[n4] = MFMA(asp, brh, accR[n4]);
            }
        }
        #pragma unroll 2
        for (int s = 0; s < 16; ++s) {          // o1 h1y half (fc2 rows 512..1023)
            const s16x8 ah = LDSA(h1hi, s), al = LDSA(h1lo, s);
            #pragma unroll
            for (int n4 = 0; n4 < 2; ++n4) {
                const int n = wid * 2 + n4;
                const s16x8 bsh = GLB(O_FC2S_HI, s + 16, n);
                const s16x8 brh = GLB(O_FC2R_HI, s + 16, n);
                accS[n4] = MFMA(ah, bsh, accS[n4]);
                accS[n4] = MFMA(al, bsh, accS[n4]);
                accR[n4] = MFMA(ah, brh, accR[n4]);
                accR[n4] = MFMA(al, brh, accR[n4]);
            }
        }
        #pragma unroll 2
        for (int s = 0; s < 16; ++s) {          // h2y_prev @ fv2
            const s16x8 ah = LDSA(h2hi, s), al = LDSA(h2lo, s);
            #pragma unroll
            for (int n4 = 0; n4 < 2; ++n4) {
                const int n = wid * 2 + n4;
                const s16x8 bh = GLB(O_FV2_HI, s, n);
                accR[n4] = MFMA(ah, bh, accR[n4]);
                accR[n4] = MFMA(al, bh, accR[n4]);
            }
        }
        // membrane 2 update
        #pragma unroll
        for (int n4 = 0; n4 < 2; ++n4) {
            #pragma unroll
            for (int r = 0; r < 4; ++r) {
                float mem = h2mem[n4][r];
                mem = (mem > THRESH ? 0.0f : mem * DECAY) + accS[n4][r];
                h2mem[n4][r] = mem;
                h2sum[n4][r] += (mem > THRESH) ? 1.0f : 0.0f;
                const float y = 1.0f / (1.0f + expf(-accR[n4][r]));
                const unsigned short h = f2bf(y);
                yh[n4][r] = h;
                yl[n4][r] = f2bf(y - bf2f(h));
            }
        }
        __syncthreads();   // (D) all fv2 reads of old h2 arrays done
        #pragma unroll
        for (int n4 = 0; n4 < 2; ++n4) {
            const int col = (wid * 2 + n4) * 16 + lrow;
            #pragma unroll
            for (int r = 0; r < 4; ++r) {
                const int row = lgrp * 4 + r;
                const int wc  = row * 512 + (col ^ ((row & 7) << 3));
                h2hi[wc] = yh[n4][r];
                h2lo[wc] = yl[n4][r];
            }
        }
        // visibility for next step's fv2 reads is barrier (A)
    }
    __syncthreads();

    // ---- epilogue ----
    float* sums = sh_x;   // reuse x slab (fp32 [16][512])
    #pragma unroll
    for (int n4 = 0; n4 < 2; ++n4) {
        const int col = (wid * 2 + n4) * 16 + lrow;
        #pragma unroll
        for (int r = 0; r < 4; ++r)
            sums[(lgrp * 4 + r) * NH + col] = h2sum[n4][r] * (1.0f / (float)TSTEPS);
    }
    const size_t L_OFF  = (size_t)BTOT * 10;
    const size_t H2_OFF = L_OFF + (size_t)BTOT * NH;
    for (int i = tid; i < BR * NH; i += NTHREADS) {
        const int r = i >> 9, c = i & 511;
        const int sc = r * 512 + (c ^ ((r & 7) << 3));
        out[L_OFF  + (size_t)(rb + r) * NH + c] = bf2f(h1hi[sc]) + bf2f(h1lo[sc]);
        out[H2_OFF + (size_t)(rb + r) * NH + c] = bf2f(h2hi[sc]) + bf2f(h2lo[sc]);
    }
    __syncthreads();
    if (tid < BR * 10) {
        const int r = tid / 10, c = tid % 10;
        float acc = fcb[c];
        for (int k = 0; k < NH; ++k) acc += sums[r * NH + k] * fcw[c * 1024 + k];
        for (int k = 0; k < NH; ++k) {
            const int sc = r * 512 + (k ^ ((r & 7) << 3));
            acc += (bf2f(h2hi[sc]) + bf2f(h2lo[sc])) * fcw[c * 1024 + NH + k];
        }
        out[(size_t)(rb + r) * 10 + c] = acc;
    }
}

extern "C" void kernel_launch(void* const* d_in, const int* in_sizes, int n_in,
                              void* d_out, int out_size, void* d_ws, size_t ws_size,
                              hipStream_t stream) {
    (void)in_sizes; (void)n_in; (void)out_size; (void)ws_size;
    const float* x    = (const float*)d_in[0];
    // d_in[1], d_in[2] (hidden1/hidden2) zero-valued, unused by reference math
    const float* fc1s = (const float*)d_in[3];
    const float* fc2s = (const float*)d_in[4];
    const float* fc1r = (const float*)d_in[5];
    const float* fc2r = (const float*)d_in[6];
    const float* fv1  = (const float*)d_in[7];
    const float* fv2  = (const float*)d_in[8];
    const float* fcw  = (const float*)d_in[9];
    const float* fcb  = (const float*)d_in[10];
    float* out = (float*)d_out;
    unsigned short* pk = (unsigned short*)d_ws;     // 3.80 MB packed weights (L2-resident)

    hipLaunchKernelGGL(pack_w, dim3((200704 + 255) / 256), dim3(256), 0, stream,
                       fc1s, fc1r, fv1, fv2, fc2s, fc2r, pk);

    const size_t smem = (size_t)(BR * 784) * sizeof(float)
                      + (size_t)(5 * BR * 512 + 2 * BR * XS) * sizeof(unsigned short); // 134,656 B
    hipFuncSetAttribute(reinterpret_cast<const void*>(hnn_mfma),
                        hipFuncAttributeMaxDynamicSharedMemorySize, (int)smem);
    hipLaunchKernelGGL(hnn_mfma, dim3(BTOT / BR), dim3(NTHREADS), smem, stream,
                       x, pk, fcw, fcb, out);
}